// Round 10
// baseline (82.220 us; speedup 1.0000x reference)
//
#include <hip/hip_runtime.h>

// B=64, D=2048, UNITS=1024, NW=64; L = in_sizes[3]/(UNITS*NW) (~56).
//
// out[b,u] = sum_i x[b,i] * W[u,i] + bias[u], W[u,i] = w[k] where bucket k of
// unit u contains position i (indices 1-shifted, 0 = pad).
//
// R10 vs R9 post-mortem: configs invariant (R4/R7/R8/R9 all ~81 bench,
// kernel ~25-28us) across occupancy 16->32 waves, 2x x-reuse, 2x indices
// traffic. Remaining shared cost: the serial per-block chain
// zero -> barrier -> scatter -> barrier -> compute. R10 collapses it to ONE
// barrier: wave w (w<8) OWNS LDS row w end-to-end (zero, load its 64 buckets
// with 64 loads in flight = 4x the MLP, scatter). Same-wave DS ops are
// in-order -> no barrier between zero and scatter. w[] broadcast via __shfl
// from a register (no w_lds dependency). Phase 2 = R9's (best measured).

#define B_DIM   64
#define D_DIM   2048
#define D4      (D_DIM / 4)     // 512 float4 per row
#define UNITS_N 1024
#define NW_N    64
#define U_PER_BLOCK 8
#define B_SPLIT 2
#define B_PER_BLOCK (B_DIM / B_SPLIT)               // 32
#define THREADS 1024
#define WAVES   (THREADS / 64)                      // 16
#define ROWS_PER_WAVE  (B_PER_BLOCK / WAVES)        // 2
#define STEPS   (D4 / 64)                           // 8

__global__ __launch_bounds__(THREADS)   // NO 2nd arg: 64-VGPR cap + spill (R5)
void EfficientHashedLinear_72043781423546_kernel(
    const float* __restrict__ x,        // (64, 2048)
    const float* __restrict__ w,        // (64,)
    const float* __restrict__ bias,     // (1024,)
    const int*   __restrict__ indices,  // (UNITS, NW, L) int32
    float*       __restrict__ out,      // (64, 1024)
    int L)
{
    __shared__ float rows[U_PER_BLOCK][D_DIM];   // 64 KB

    const int tid  = threadIdx.x;
    const int wave = tid >> 6;          // 0..15
    const int lane = tid & 63;
    const int u0   = blockIdx.x * U_PER_BLOCK;
    const int bh   = blockIdx.y;        // batch half: 0 or 1

    if (wave < U_PER_BLOCK) {
        // This wave owns LDS row `wave` end-to-end: zero -> load -> scatter.
        // Same-wave DS ops complete in order; no barrier needed until the
        // block-wide one before phase 2.
        float* row = rows[wave];

        // Zero own row (8 float4 stores/lane).
        {
            float4* r4 = (float4*)row;
            const float4 z = make_float4(0.f, 0.f, 0.f, 0.f);
            #pragma unroll
            for (int i = lane; i < D4; i += 64)
                r4[i] = z;
        }

        // w broadcast source: lane k holds w[k] (NW == 64 == wavefront).
        const float wv = w[lane];

        // Load all 64 buckets of this row — 64 independent predicated loads
        // in flight (4x the MLP of the R9 scheme).
        const int* bp0 = indices + ((size_t)(u0 + wave) * NW_N) * L;
        int idxv[NW_N];
        #pragma unroll
        for (int k = 0; k < NW_N; ++k)
            idxv[k] = (lane < L) ? bp0[(size_t)k * L + lane] : 0;

        // Scatter own row (LDS only; wk via cross-lane broadcast).
        #pragma unroll
        for (int k = 0; k < NW_N; ++k) {
            const float wk = __shfl(wv, k, 64);
            if (idxv[k] > 0) row[idxv[k] - 1] = wk;
        }

        // Generic tail for L > 64 (not expected; kept for safety).
        if (L > 64) {
            #pragma unroll 1
            for (int k = 0; k < NW_N; ++k) {
                const float wk = __shfl(wv, k, 64);
                const int* bp = bp0 + (size_t)k * L;
                for (int l = 64 + lane; l < L; l += 64) {
                    int idx = bp[l];
                    if (idx > 0) row[idx - 1] = wk;
                }
            }
        }
    }

    __syncthreads();   // the ONLY barrier

    // Phase 2: wave owns 2 batch rows (of this half's 32) x 8 units.
    const int b0 = bh * B_PER_BLOCK + wave * ROWS_PER_WAVE;
    const float4* x4 = (const float4*)x;

    float acc[ROWS_PER_WAVE][U_PER_BLOCK];
    #pragma unroll
    for (int bj = 0; bj < ROWS_PER_WAVE; ++bj)
        #pragma unroll
        for (int uu = 0; uu < U_PER_BLOCK; ++uu)
            acc[bj][uu] = 0.0f;

    #pragma unroll 1   // keep live set small; big unrolls spill (R2/R5)
    for (int step = 0; step < STEPS; ++step) {
        const int i4 = step * 64 + lane;          // 0..511
        float4 xv[ROWS_PER_WAVE];
        #pragma unroll
        for (int bj = 0; bj < ROWS_PER_WAVE; ++bj)
            xv[bj] = x4[(b0 + bj) * D4 + i4];
        #pragma unroll
        for (int uu = 0; uu < U_PER_BLOCK; ++uu) {
            const float4 rv = ((const float4*)rows[uu])[i4];   // ds_read_b128
            #pragma unroll
            for (int bj = 0; bj < ROWS_PER_WAVE; ++bj) {
                acc[bj][uu] += xv[bj].x * rv.x;
                acc[bj][uu] += xv[bj].y * rv.y;
                acc[bj][uu] += xv[bj].z * rv.z;
                acc[bj][uu] += xv[bj].w * rv.w;
            }
        }
    }

    // Phase 3: butterfly reduce, add bias, store (16 outputs/wave).
    #pragma unroll
    for (int bj = 0; bj < ROWS_PER_WAVE; ++bj) {
        #pragma unroll
        for (int uu = 0; uu < U_PER_BLOCK; ++uu) {
            float v = acc[bj][uu];
            #pragma unroll
            for (int off = 32; off > 0; off >>= 1)
                v += __shfl_down(v, off, 64);
            if (lane == 0)
                out[(b0 + bj) * UNITS_N + (u0 + uu)] = v + bias[u0 + uu];
        }
    }
}

extern "C" void kernel_launch(void* const* d_in, const int* in_sizes, int n_in,
                              void* d_out, int out_size, void* d_ws, size_t ws_size,
                              hipStream_t stream) {
    const float* x       = (const float*)d_in[0];
    const float* w       = (const float*)d_in[1];
    const float* bias    = (const float*)d_in[2];
    const int*   indices = (const int*)d_in[3];
    float*       out     = (float*)d_out;

    const int L = in_sizes[3] / (UNITS_N * NW_N);

    dim3 grid(UNITS_N / U_PER_BLOCK, B_SPLIT);  // (128, 2) = 256 blocks = 1/CU
    dim3 block(THREADS);                        // 1024 threads = 16 waves
    EfficientHashedLinear_72043781423546_kernel<<<grid, block, 0, stream>>>(
        x, w, bias, indices, out, L);
}